// Round 2
// baseline (1462.748 us; speedup 1.0000x reference)
//
#include <hip/hip_runtime.h>

typedef __bf16 v8bf __attribute__((ext_vector_type(8)));
typedef float  v4f  __attribute__((ext_vector_type(4)));
typedef unsigned short us8 __attribute__((ext_vector_type(8)));

__device__ __forceinline__ float bf2f(unsigned short u) {
    union { unsigned int i; float f; } v; v.i = ((unsigned int)u) << 16; return v.f;
}
__device__ __forceinline__ unsigned short f2bf(float f) {
    union { float f; unsigned int i; } v; v.f = f;
    return (unsigned short)((v.i + 0x7fffu + ((v.i >> 16) & 1u)) >> 16);
}

// ------- transpose+downcast: dst[n][k] = bf16(src[k][n]); K,N mult of 64 ----
__global__ __launch_bounds__(256)
void transpose_f32_bf16(const float* __restrict__ src,
                        unsigned short* __restrict__ dst, int K, int N)
{
    __shared__ unsigned short tile[64][72];
    const int tid = threadIdx.x;
    const int c0 = blockIdx.x * 64, r0 = blockIdx.y * 64;
    const int tr = tid >> 2, tc4 = tid & 3;
    const float* sp = src + (size_t)(r0 + tr) * N + c0 + tc4 * 16;
#pragma unroll
    for (int j = 0; j < 4; ++j) {
        v4f f = *reinterpret_cast<const v4f*>(sp + j * 4);
#pragma unroll
        for (int e = 0; e < 4; ++e) tile[tr][tc4 * 16 + j * 4 + e] = f2bf(f[e]);
    }
    __syncthreads();
    const int ow = tid >> 3, och = tid & 7;
#pragma unroll
    for (int p = 0; p < 2; ++p) {
        int orow = p * 32 + ow;
        us8 o;
#pragma unroll
        for (int e = 0; e < 8; ++e) o[e] = tile[och * 8 + e][orow];
        *reinterpret_cast<us8*>(dst + (size_t)(c0 + orow) * K + r0 + och * 8) = o;
    }
}

// ------- BM=64 GEMM; B given transposed (BT[n][k]); A/B fp32 or bf16 -------
// A row ptr = A + (m&63)*lda_lo + (m>>6)*lda_hi   (strides in elements)
template<int BN, bool STORE_BF16, bool AF32, bool BF32>
__global__ __launch_bounds__(256, 2)
void gemm_bt(const void* __restrict__ Ap, int lda_lo, int lda_hi,
             const void* __restrict__ BTp, int ldb,
             void* __restrict__ Cout, int ldc,
             int ksub, long long csplit_stride)
{
    constexpr int FN  = BN / 32;
    constexpr int BCH = BN / 32;
    const int tid = threadIdx.x;
    const int lane = tid & 63, wid = tid >> 6;
    const int wr = wid >> 1, wc = wid & 1;
    const int nt = blockIdx.x, mt = blockIdx.y, kz = blockIdx.z;
    const int n0 = nt * BN;
    const int kstart = kz * ksub;

    __shared__ unsigned short smem[(64 + BN) * 64];
    char* As = reinterpret_cast<char*>(smem);
    char* Bs = reinterpret_cast<char*>(smem + 64 * 64);

    const unsigned short* A16 = (const unsigned short*)Ap;
    const float*          A32 = (const float*)Ap;
    const unsigned short* B16 = (const unsigned short*)BTp;
    const float*          B32 = (const float*)BTp;

    // A addressing
    const int arow = AF32 ? (tid >> 2) : (tid >> 3);
    const int aq   = AF32 ? (tid & 3) : (tid & 7);
    const float* Ab32 = A32 + (size_t)arow * lda_lo + (size_t)mt * lda_hi + kstart + aq * 16;
    const unsigned short* Ab16 = A16 + (size_t)arow * lda_lo + (size_t)mt * lda_hi + kstart + aq * 8;
    // B addressing
    const int brow = tid >> 3, bq = tid & 7;
    const float* Bb32 = B32 + (size_t)(n0 + brow) * ldb + kstart + bq * 8;
    const unsigned short* Bb16 = B16 + (size_t)(n0 + brow) * ldb + kstart + bq * 8;

    v4f fa[4];          // AF32 regs
    us8 ra[2];          // A bf16 regs
    v4f fb[BCH][2];     // BF32 regs
    us8 rb[BCH];        // B bf16 regs

    auto load = [&](int kk) {
        if (AF32) {
#pragma unroll
            for (int j = 0; j < 4; ++j)
                fa[j] = *reinterpret_cast<const v4f*>(Ab32 + kk + j * 4);
        } else {
#pragma unroll
            for (int p = 0; p < 2; ++p)
                ra[p] = *reinterpret_cast<const us8*>(Ab16 + (size_t)(p * 32) * lda_lo + kk);
        }
        if (BF32) {
#pragma unroll
            for (int p = 0; p < BCH; ++p) {
                fb[p][0] = *reinterpret_cast<const v4f*>(Bb32 + (size_t)(p * 32) * ldb + kk);
                fb[p][1] = *reinterpret_cast<const v4f*>(Bb32 + (size_t)(p * 32) * ldb + kk + 4);
            }
        } else {
#pragma unroll
            for (int p = 0; p < BCH; ++p)
                rb[p] = *reinterpret_cast<const us8*>(Bb16 + (size_t)(p * 32) * ldb + kk);
        }
    };
    auto stage = [&]() {
        if (AF32) {
#pragma unroll
            for (int h = 0; h < 2; ++h) {
                us8 v;
#pragma unroll
                for (int e = 0; e < 8; ++e) v[e] = f2bf(fa[h * 2 + (e >> 2)][e & 3]);
                *reinterpret_cast<us8*>(As + arow * 128 + (((aq * 2 + h) * 16) ^ ((arow & 7) << 4))) = v;
            }
        } else {
#pragma unroll
            for (int p = 0; p < 2; ++p)
                *reinterpret_cast<us8*>(As + (arow + p * 32) * 128 + ((aq * 16) ^ ((arow & 7) << 4))) = ra[p];
        }
#pragma unroll
        for (int p = 0; p < BCH; ++p) {
            us8 v;
            if (BF32) {
#pragma unroll
                for (int e = 0; e < 8; ++e) v[e] = f2bf(fb[p][e >> 2][e & 3]);
            } else v = rb[p];
            *reinterpret_cast<us8*>(Bs + (brow + p * 32) * 128 + ((bq * 16) ^ ((brow & 7) << 4))) = v;
        }
    };

    v4f z4 = {0.f, 0.f, 0.f, 0.f};
    v4f acc[2][FN];
#pragma unroll
    for (int i = 0; i < 2; ++i)
#pragma unroll
        for (int j = 0; j < FN; ++j) acc[i][j] = z4;

    const int l15 = lane & 15, l4 = lane >> 4;
    const int nk = ksub / 64;
    load(0);
    for (int it = 0; it < nk; ++it) {
        __syncthreads();
        stage();
        __syncthreads();
        if (it + 1 < nk) load((it + 1) * 64);
#pragma unroll
        for (int ks = 0; ks < 2; ++ks) {
            const int kb = (ks * 32 + l4 * 8) * 2;
            v8bf af[2], bfr[FN];
#pragma unroll
            for (int fm = 0; fm < 2; ++fm) {
                int row = wr * 32 + fm * 16 + l15;
                af[fm] = *reinterpret_cast<const v8bf*>(As + row * 128 + (kb ^ ((row & 7) << 4)));
            }
#pragma unroll
            for (int fn = 0; fn < FN; ++fn) {
                int row = wc * (BN / 2) + fn * 16 + l15;
                bfr[fn] = *reinterpret_cast<const v8bf*>(Bs + row * 128 + (kb ^ ((row & 7) << 4)));
            }
#pragma unroll
            for (int fm = 0; fm < 2; ++fm)
#pragma unroll
                for (int fn = 0; fn < FN; ++fn)
                    acc[fm][fn] = __builtin_amdgcn_mfma_f32_16x16x32_bf16(af[fm], bfr[fn], acc[fm][fn], 0, 0, 0);
        }
    }
    const long long m0 = (long long)mt * 64;
#pragma unroll
    for (int fm = 0; fm < 2; ++fm)
#pragma unroll
        for (int fn = 0; fn < FN; ++fn)
#pragma unroll
            for (int r = 0; r < 4; ++r) {
                long long row = m0 + wr * 32 + fm * 16 + l4 * 4 + r;
                long long col = n0 + wc * (BN / 2) + fn * 16 + l15;
                long long idx = (long long)kz * csplit_stride + row * ldc + col;
                if (STORE_BF16) reinterpret_cast<unsigned short*>(Cout)[idx] = f2bf(acc[fm][fn][r]);
                else            reinterpret_cast<float*>(Cout)[idx]          = acc[fm][fn][r];
            }
}

// ------- scan combine: pre = sum(parts) + xu; h = tanh(pre) ----------------
__global__ __launch_bounds__(256)
void scan_combine(const float* __restrict__ part, int nparts,
                  const unsigned short* __restrict__ xu,
                  unsigned short* __restrict__ hcur,
                  unsigned short* __restrict__ Hbf, int t)
{
    int i = blockIdx.x * 256 + threadIdx.x;       // over 64*8192
    float pre = xu ? bf2f(xu[i]) : 0.f;
    for (int z = 0; z < nparts; ++z) pre += part[(size_t)z * 524288 + i];
    float h = tanhf(pre);
    unsigned short hb = f2bf(h);
    hcur[i] = hb;
    int b = i >> 13, r = i & 8191;
    int c = r >> 10, pp = r & 1023;
    Hbf[(((size_t)b * 8 + c) * 20 + t) * 1024 + pp] = hb;   // (B,8,T,32,32)
}

// ------- conv1: (B,8,T,32,32) -> (B,64,T,16,16), 3x3x3 s(1,2,2) p1 ---------
__global__ __launch_bounds__(256, 1)
void conv1_kernel(const unsigned short* __restrict__ H,
                  const float* __restrict__ w,
                  const float* __restrict__ bias,
                  unsigned short* __restrict__ y1)
{
    const int b = blockIdx.x, t = blockIdx.y;
    const int tid = threadIdx.x, lane = tid & 63, wid = tid >> 6;
    __shared__ unsigned short in_s[24 * 34 * 34];   // (ci*3+dt) x 34 x 34
    __shared__ unsigned short w_s[64 * 320];        // [64][288] @320 stride, swizzled

    for (int i = tid; i < 24 * 34 * 34; i += 256) in_s[i] = 0;
    __syncthreads();
    for (int idx = tid; idx < 3072; idx += 256) {
        int g = idx >> 7, rem = idx & 127;
        int iy = rem >> 2, c8 = rem & 3;
        int cc = g / 3, dt = g % 3;
        int ts = t + dt - 1;
        if (ts >= 0 && ts < 20) {
            us8 v = *reinterpret_cast<const us8*>(H + (((size_t)b * 8 + cc) * 20 + ts) * 1024 + iy * 32 + c8 * 8);
            int base = g * 1156 + (iy + 1) * 34 + 1 + c8 * 8;
#pragma unroll
            for (int e = 0; e < 8; ++e) in_s[base + e] = v[e];
        }
    }
    for (int idx = tid; idx < 64 * 288; idx += 256) {
        int n = idx / 288, k = idx % 288;
        int g = k / 12, rm = k % 12, dy = rm >> 2, dx = rm & 3;
        unsigned short val = 0;
        if (dx < 3) {
            int cc = g / 3, dt = g % 3;
            val = f2bf(w[(((n * 8 + cc) * 3 + dt) * 3 + dy) * 3 + dx]);
        }
        *reinterpret_cast<unsigned short*>(reinterpret_cast<char*>(w_s) + n * 640 + ((2 * k) ^ ((n & 7) << 4))) = val;
    }
    __syncthreads();

    v4f z4 = {0.f, 0.f, 0.f, 0.f};
    v4f acc[4][4];
#pragma unroll
    for (int i = 0; i < 4; ++i)
#pragma unroll
        for (int j = 0; j < 4; ++j) acc[i][j] = z4;
    const int l15 = lane & 15, l4 = lane >> 4;

#pragma unroll
    for (int ks = 0; ks < 9; ++ks) {                // K = 288
        v8bf aw[4];
#pragma unroll
        for (int fc = 0; fc < 4; ++fc) {
            int row = fc * 16 + l15;
            aw[fc] = *reinterpret_cast<const v8bf*>(reinterpret_cast<const char*>(w_s)
                       + row * 640 + (((ks * 32 + l4 * 8) * 2) ^ ((row & 7) << 4)));
        }
        v8bf bp[4];
#pragma unroll
        for (int fm = 0; fm < 4; ++fm) {
            int m = wid * 64 + fm * 16 + l15;
            int py = m >> 4, px = m & 15;
            int k0 = ks * 32 + l4 * 8;
            union { v8bf v; unsigned int u[4]; } F;
#pragma unroll
            for (int h = 0; h < 2; ++h) {
                int c = k0 + h * 4;
                int g = c / 12, rm2 = c % 12, dy = rm2 >> 2;
                const char* p = reinterpret_cast<const char*>(in_s)
                                + 2 * (g * 1156 + (2 * py + dy) * 34 + 2 * px);
                F.u[h * 2 + 0] = *reinterpret_cast<const unsigned int*>(p);
                F.u[h * 2 + 1] = *reinterpret_cast<const unsigned int*>(p + 4);
            }
            bp[fm] = F.v;
        }
#pragma unroll
        for (int fc = 0; fc < 4; ++fc)
#pragma unroll
            for (int fm = 0; fm < 4; ++fm)
                acc[fc][fm] = __builtin_amdgcn_mfma_f32_16x16x32_bf16(aw[fc], bp[fm], acc[fc][fm], 0, 0, 0);
    }
#pragma unroll
    for (int fc = 0; fc < 4; ++fc)
#pragma unroll
        for (int fm = 0; fm < 4; ++fm)
#pragma unroll
            for (int r = 0; r < 4; ++r) {
                int co = fc * 16 + l4 * 4 + r;
                int m  = wid * 64 + fm * 16 + l15;
                float v = acc[fc][fm][r] + bias[co];
                v = v > 0.f ? v : 0.01f * v;
                y1[(((size_t)b * 64 + co) * 20 + t) * 256 + m] = f2bf(v);
            }
}

// ------- conv2: (B,64,T,16,16) -> (B,128,T,7,7), 3x4x4 s(1,2,2) p(1,0,0) ---
__global__ __launch_bounds__(256, 1)
void conv2_kernel(const unsigned short* __restrict__ y1,
                  const float* __restrict__ w,
                  const float* __restrict__ bias,
                  unsigned short* __restrict__ y2)
{
    const int b = blockIdx.x, t = blockIdx.y;
    const int tid = threadIdx.x, lane = tid & 63, wid = tid >> 6;
    const int wr = wid >> 1, wc = wid & 1;
    __shared__ unsigned short in_s[64 * 768];    // [ci][dt][16][16]
    __shared__ unsigned short w_s[128 * 64];     // weight K-chunk, swizzled

    for (int idx = tid; idx < 6144; idx += 256) {
        int ci = idx / 96, rem = idx % 96;
        int dt = rem / 32, r2 = rem % 32;
        int iy = r2 >> 1, c8 = r2 & 1;
        int ts = t + dt - 1;
        us8 v = {0, 0, 0, 0, 0, 0, 0, 0};
        if (ts >= 0 && ts < 20)
            v = *reinterpret_cast<const us8*>(y1 + (((size_t)b * 64 + ci) * 20 + ts) * 256 + iy * 16 + c8 * 8);
        *reinterpret_cast<us8*>(&in_s[ci * 768 + dt * 256 + iy * 16 + c8 * 8]) = v;
    }

    v4f z4 = {0.f, 0.f, 0.f, 0.f};
    v4f acc[4][2];
#pragma unroll
    for (int i = 0; i < 4; ++i)
#pragma unroll
        for (int j = 0; j < 2; ++j) acc[i][j] = z4;
    const int l15 = lane & 15, l4 = lane >> 4;
    const int wsrow = tid >> 3, wsch = tid & 7;

    for (int kc = 0; kc < 48; ++kc) {            // K = 3072 in chunks of 64
        __syncthreads();
#pragma unroll
        for (int p = 0; p < 4; ++p) {
            int row = p * 32 + wsrow;
            const float* wp = w + (size_t)row * 3072 + kc * 64 + wsch * 8;
            v4f f0 = *reinterpret_cast<const v4f*>(wp);
            v4f f1 = *reinterpret_cast<const v4f*>(wp + 4);
            us8 v;
#pragma unroll
            for (int e = 0; e < 8; ++e) v[e] = f2bf(e < 4 ? f0[e] : f1[e - 4]);
            *reinterpret_cast<us8*>(reinterpret_cast<char*>(w_s) + row * 128 + ((wsch * 16) ^ ((row & 7) << 4))) = v;
        }
        __syncthreads();
#pragma unroll
        for (int ks = 0; ks < 2; ++ks) {
            int klocal = ks * 32 + l4 * 8;
            v8bf aw[4];
#pragma unroll
            for (int fc = 0; fc < 4; ++fc) {
                int row = wc * 64 + fc * 16 + l15;
                aw[fc] = *reinterpret_cast<const v8bf*>(reinterpret_cast<const char*>(w_s)
                           + row * 128 + ((klocal * 2) ^ ((row & 7) << 4)));
            }
            v8bf bp[2];
#pragma unroll
            for (int fm = 0; fm < 2; ++fm) {
                int m = wr * 32 + fm * 16 + l15;
                m = m < 49 ? m : 48;
                int py = m / 7, px = m - py * 7;
                union { v8bf v; unsigned int u[4]; } F;
#pragma unroll
                for (int h = 0; h < 2; ++h) {
                    int c = kc * 64 + klocal + h * 4;
                    int ci = c / 48, rc = c % 48;
                    int dt = rc >> 4, dy = (rc >> 2) & 3;
                    const char* p = reinterpret_cast<const char*>(in_s)
                                    + 2 * (ci * 768 + dt * 256 + (2 * py + dy) * 16 + 2 * px);
                    F.u[h * 2 + 0] = *reinterpret_cast<const unsigned int*>(p);
                    F.u[h * 2 + 1] = *reinterpret_cast<const unsigned int*>(p + 4);
                }
                bp[fm] = F.v;
            }
#pragma unroll
            for (int fc = 0; fc < 4; ++fc)
#pragma unroll
                for (int fm = 0; fm < 2; ++fm)
                    acc[fc][fm] = __builtin_amdgcn_mfma_f32_16x16x32_bf16(aw[fc], bp[fm], acc[fc][fm], 0, 0, 0);
        }
    }
#pragma unroll
    for (int fc = 0; fc < 4; ++fc)
#pragma unroll
        for (int fm = 0; fm < 2; ++fm)
#pragma unroll
            for (int r = 0; r < 4; ++r) {
                int m = wr * 32 + fm * 16 + l15;
                if (m < 49) {
                    int co = wc * 64 + fc * 16 + l4 * 4 + r;
                    float v = acc[fc][fm][r] + bias[co];
                    v = v > 0.f ? v : 0.01f * v;
                    y2[(((size_t)b * 128 + co) * 20 + t) * 49 + m] = f2bf(v);
                }
            }
}

// ------- linear epilogue: +bias, split mu/logvar, fp32 out -----------------
__global__ __launch_bounds__(256)
void lin_epi(const float* __restrict__ linC, const float* __restrict__ lb,
             float* __restrict__ out)
{
    int i = blockIdx.x * 256 + threadIdx.x;      // 0..327679
    int m = i >> 8, n = i & 255;                 // m = b*20+t
    float v = linC[i] + lb[n];
    size_t o = (n < 128) ? ((size_t)m * 128 + n) : (163840 + (size_t)m * 128 + (n - 128));
    out[o] = v;
}

extern "C" void kernel_launch(void* const* d_in, const int* in_sizes, int n_in,
                              void* d_out, int out_size, void* d_ws, size_t ws_size,
                              hipStream_t stream)
{
    const float* x   = (const float*)d_in[0];  // (64,20,64,64)
    const float* Win = (const float*)d_in[1];  // (4096,8192)
    const float* U   = (const float*)d_in[2];  // (4096,8192)
    const float* Wr  = (const float*)d_in[3];  // (8192,8192)
    const float* c1w = (const float*)d_in[4];
    const float* c1b = (const float*)d_in[5];
    const float* c2w = (const float*)d_in[6];
    const float* c2b = (const float*)d_in[7];
    const float* lw  = (const float*)d_in[8];  // (256,6272) == B^T
    const float* lb  = (const float*)d_in[9];

    char* ws = (char*)d_ws;
    unsigned short* WrT  = (unsigned short*)(ws);                   // 128 MB bf16
    unsigned short* WT   = (unsigned short*)(ws + 134217728ll);     // 64 MB (WinT then UT)
    unsigned short* y1   = (unsigned short*)(ws + 134217728ll);     // reuse (41.9 MB)
    unsigned short* y2   = (unsigned short*)(ws + 176160768ll);     // 12.85 MB
    unsigned short* XALL = (unsigned short*)(ws + 201326592ll);     // 21 MB [20][64][8192] bf16
    unsigned short* Hbf  = (unsigned short*)(ws + 222298112ll);     // 21 MB (B,8,20,32,32)
    float*          part = (float*)        (ws + 243269632ll);      // 8.4 MB [4][64][8192] f32
    unsigned short* hcur = (unsigned short*)(ws + 251658240ll);     // 1 MB
    float*          linC = (float*)        (ws + 252706816ll);      // 1.3 MB
    float*          out  = (float*)d_out;

    // --- h0 path: transpose Win (fp32->bf16), GEMM split-K 4, tanh combine
    transpose_f32_bf16<<<dim3(128, 64), 256, 0, stream>>>(Win, WT, 4096, 8192);
    gemm_bt<128, false, true, false><<<dim3(64, 1, 4), 256, 0, stream>>>(
        x, 81920, 0, WT, 4096, part, 8192, 1024, 524288ll);
    scan_combine<<<2048, 256, 0, stream>>>(part, 4, (const unsigned short*)nullptr, hcur, Hbf, 0);

    // --- xU = x[:,1:] @ U  -> XALL slots 1..19 (bf16)
    transpose_f32_bf16<<<dim3(128, 64), 256, 0, stream>>>(U, WT, 4096, 8192);
    gemm_bt<128, true, true, false><<<dim3(64, 19, 1), 256, 0, stream>>>(
        x + 4096, 81920, 4096, WT, 4096, XALL + 524288, 8192, 4096, 0ll);

    // --- reservoir scan
    transpose_f32_bf16<<<dim3(128, 128), 256, 0, stream>>>(Wr, WrT, 8192, 8192);
    for (int t = 1; t < 20; ++t) {
        gemm_bt<64, false, false, false><<<dim3(128, 1, 4), 256, 0, stream>>>(
            hcur, 8192, 0, WrT, 8192, part, 8192, 2048, 524288ll);
        scan_combine<<<2048, 256, 0, stream>>>(part, 4, XALL + (size_t)t * 524288, hcur, Hbf, t);
    }

    // --- convs
    conv1_kernel<<<dim3(64, 20), 256, 0, stream>>>(Hbf, c1w, c1b, y1);
    conv2_kernel<<<dim3(64, 20), 256, 0, stream>>>(y1, c2w, c2b, y2);

    // --- linear head: A = y2 viewed as [1280][6272] bf16, BT = lin_w fp32
    gemm_bt<128, false, false, true><<<dim3(2, 20, 1), 256, 0, stream>>>(
        y2, 6272, 6272 * 64, lw, 6272, linC, 256, 6272, 0ll);
    lin_epi<<<1280, 256, 0, stream>>>(linC, lb, out);
}